// Round 7
// baseline (124.436 us; speedup 1.0000x reference)
//
#include <hip/hip_runtime.h>
#include <math.h>

#define BB 8
#define QQ 100
#define CC 41
#define TT 50
#define PP 12544        // = 49 * 256
#define QP 112          // padded Q rows (7 * 16)
#define TP 64           // padded T rows (4 * 16)
#define KS 8            // split-K over P
#define KCH (PP / KS)   // 1568
#define NT (BB * TT)    // 400
#define NMASK (NT + BB * QQ)   // 1200
#define MPB 5           // masks per persistent block
#define SGRID (NMASK / MPB)    // 240

typedef _Float16 f16x8 __attribute__((ext_vector_type(8)));
typedef float f32x4 __attribute__((ext_vector_type(4)));

#if defined(__has_builtin)
#if __has_builtin(__builtin_amdgcn_cvt_pk_fp8_f32) && __has_builtin(__builtin_amdgcn_cvt_f32_fp8)
#define HAVE_FP8CVT 1
#endif
#endif

__device__ __forceinline__ unsigned int cvt1_e4m3_sw(float x) {
    unsigned int u = __float_as_uint(x);
    unsigned int s = (u >> 24) & 0x80u;
    float ax = fminf(fabsf(x), 448.f);
    if (ax < 0.015625f) {
        unsigned int m = (unsigned int)rintf(ax * 512.f);
        return s | m;
    }
    unsigned int v = __float_as_uint(ax);
    v += 0x7FFFFu + ((v >> 20) & 1u);
    int e = (int)(v >> 23) - 127;
    unsigned int m = (v >> 20) & 7u;
    if (e < -6) { m = (unsigned int)rintf(ax * 512.f); return s | m; }
    unsigned int ee = (unsigned int)(e + 7);
    if (ee >= 16u) { ee = 15u; m = 6u; }
    return s | (ee << 3) | m;
}

template <bool HI>
__device__ __forceinline__ unsigned int pack2_e4m3(float a, float b, unsigned int old) {
#ifdef HAVE_FP8CVT
    return (unsigned int)__builtin_amdgcn_cvt_pk_fp8_f32(a, b, (int)old, HI);
#else
    unsigned int p = (cvt1_e4m3_sw(a) | (cvt1_e4m3_sw(b) << 8)) << (HI ? 16 : 0);
    unsigned int mask = HI ? 0x0000FFFFu : 0xFFFF0000u;
    return (old & mask) | p;
#endif
}

__device__ __forceinline__ float e4m3_to_f32(unsigned int byte) {
#ifdef HAVE_FP8CVT
    return __builtin_amdgcn_cvt_f32_fp8((int)byte, 0);
#else
    unsigned int s = byte >> 7, e = (byte >> 3) & 15u, m = byte & 7u;
    float v = e ? __uint_as_float(((e + 120u) << 23) | (m << 20))
                : (float)m * 0.001953125f;
    return s ? -v : v;
#endif
}

__device__ __forceinline__ void addr_w(float2 c, int& a00, int& a01, int& a10, int& a11,
                                       float& xa, float& xb, float& ya, float& yb) {
    float x = fmaf(c.x, 256.f, -0.5f);
    float y = fmaf(c.y, 256.f, -0.5f);
    float x0f = floorf(x), y0f = floorf(y);
    float wx = x - x0f, wy = y - y0f;
    int x0 = (int)x0f, y0 = (int)y0f;
    float fx0 = (x0 >= 0) ? 1.f : 0.f, fx1 = (x0 < 255) ? 1.f : 0.f;
    float fy0 = (y0 >= 0) ? 1.f : 0.f, fy1 = (y0 < 255) ? 1.f : 0.f;
    int x0c = max(x0, 0), x1c = min(x0 + 1, 255);
    int r0 = max(y0, 0) << 8, r1 = min(y0 + 1, 255) << 8;
    a00 = r0 + x0c; a01 = r0 + x1c; a10 = r1 + x0c; a11 = r1 + x1c;
    xa = (1.f - wx) * fx0; xb = wx * fx1;
    ya = (1.f - wy) * fy0; yb = wy * fy1;
}

// Persistent double-buffered sampler: 240 blocks x 5 masks, 2x64KB fp8 LDS bufs.
__global__ __launch_bounds__(1024, 4) void sample_kernel(
    const float* __restrict__ tgt_masks, const float* __restrict__ pred_masks,
    const float* __restrict__ coords,
    _Float16* __restrict__ tm, _Float16* __restrict__ om, _Float16* __restrict__ sg,
    float* __restrict__ tmsum, float* __restrict__ nsum, float* __restrict__ ssum)
{
    __shared__ unsigned int buf[2][16384];   // 2 x 65536 B
    __shared__ float red[16], red2[16];
    int tid = threadIdx.x;
    int base = blockIdx.x * MPB;

    // ---- prologue: stage mask `base` into buf[0] ----
    {
        const float* m0 = (base < NT) ? tgt_masks + (size_t)base * 65536
                                      : pred_masks + (size_t)(base - NT) * 65536;
        const float4* s4 = (const float4*)m0;
        for (int half = 0; half < 2; ++half) {
            float4 r[8];
            #pragma unroll
            for (int k = 0; k < 8; ++k) r[k] = s4[half * 8192 + k * 1024 + tid];
            #pragma unroll
            for (int k = 0; k < 8; ++k) {
                unsigned int pk = pack2_e4m3<false>(r[k].x, r[k].y, 0u);
                buf[0][half * 8192 + k * 1024 + tid] = pack2_e4m3<true>(r[k].z, r[k].w, pk);
            }
        }
    }
    __syncthreads();

    for (int j = 0; j < MPB; ++j) {
        int id = base + j;
        bool is_t = id < NT;
        int b;
        _Float16* dst;
        _Float16* dsg = nullptr;
        if (is_t) {
            b = id / TT;
            dst = tm + ((size_t)b * TP + (id % TT)) * PP;
        } else {
            int bq = id - NT;
            b = bq / QQ;
            dst = om + ((size_t)b * QP + (bq % QQ)) * PP;
            dsg = sg + ((size_t)b * QP + (bq % QQ)) * PP;
        }
        const float2* cd = (const float2*)coords + (size_t)b * PP;
        const unsigned char* curb = (const unsigned char*)buf[j & 1];
        unsigned int* nxt = buf[(j + 1) & 1];
        bool has_next = (j + 1 < MPB);
        const float4* ns4 = nullptr;
        if (has_next) {
            int nid = id + 1;
            ns4 = (const float4*)((nid < NT) ? tgt_masks + (size_t)nid * 65536
                                             : pred_masks + (size_t)(nid - NT) * 65536);
        }

        float l1 = 0.f, l2 = 0.f;
        for (int half = 0; half < 2; ++half) {
            float4 r[8];
            if (has_next) {
                #pragma unroll
                for (int k = 0; k < 8; ++k) r[k] = ns4[half * 8192 + k * 1024 + tid];
            }
            #pragma unroll
            for (int pr = 0; pr < 3; ++pr) {
                int p1 = (half * 6 + pr * 2) * 1024 + tid;
                int p2 = p1 + 1024;
                float2 c1 = cd[p1], c2 = cd[p2];
                int a00, a01, a10, a11, e00, e01, e10, e11;
                float xa1, xb1, ya1, yb1, xa2, xb2, ya2, yb2;
                addr_w(c1, a00, a01, a10, a11, xa1, xb1, ya1, yb1);
                addr_w(c2, e00, e01, e10, e11, xa2, xb2, ya2, yb2);
                unsigned int u00 = curb[a00], u01 = curb[a01];
                unsigned int u10 = curb[a10], u11 = curb[a11];
                unsigned int w00 = curb[e00], w01 = curb[e01];
                unsigned int w10 = curb[e10], w11 = curb[e11];
                float v1 = ya1 * fmaf(xa1, e4m3_to_f32(u00), xb1 * e4m3_to_f32(u01))
                         + yb1 * fmaf(xa1, e4m3_to_f32(u10), xb1 * e4m3_to_f32(u11));
                float v2 = ya2 * fmaf(xa2, e4m3_to_f32(w00), xb2 * e4m3_to_f32(w01))
                         + yb2 * fmaf(xa2, e4m3_to_f32(w10), xb2 * e4m3_to_f32(w11));
                dst[p1] = (_Float16)v1;
                dst[p2] = (_Float16)v2;
                if (is_t) {
                    l1 += v1 + v2;
                } else {
                    float e1 = __expf(-fabsf(v1)), e2 = __expf(-fabsf(v2));
                    float q1 = 1.f / (1.f + e1), q2 = 1.f / (1.f + e2);
                    float g1 = (v1 >= 0.f) ? q1 : e1 * q1;
                    float g2 = (v2 >= 0.f) ? q2 : e2 * q2;
                    dsg[p1] = (_Float16)g1;
                    dsg[p2] = (_Float16)g2;
                    l1 += fmaxf(v1, 0.f) + __logf(1.f + e1)
                        + fmaxf(v2, 0.f) + __logf(1.f + e2);
                    l2 += g1 + g2;
                }
            }
            if (half == 1 && tid < 256) {
                int p = 12288 + tid;
                float2 c = cd[p];
                int a00, a01, a10, a11;
                float xa, xb, ya, yb;
                addr_w(c, a00, a01, a10, a11, xa, xb, ya, yb);
                float v = ya * fmaf(xa, e4m3_to_f32((unsigned int)curb[a00]),
                                    xb * e4m3_to_f32((unsigned int)curb[a01]))
                        + yb * fmaf(xa, e4m3_to_f32((unsigned int)curb[a10]),
                                    xb * e4m3_to_f32((unsigned int)curb[a11]));
                dst[p] = (_Float16)v;
                if (is_t) {
                    l1 += v;
                } else {
                    float e = __expf(-fabsf(v));
                    float q = 1.f / (1.f + e);
                    float g = (v >= 0.f) ? q : e * q;
                    dsg[p] = (_Float16)g;
                    l1 += fmaxf(v, 0.f) + __logf(1.f + e);
                    l2 += g;
                }
            }
            if (has_next) {
                #pragma unroll
                for (int k = 0; k < 8; ++k) {
                    unsigned int pk = pack2_e4m3<false>(r[k].x, r[k].y, 0u);
                    nxt[half * 8192 + k * 1024 + tid] = pack2_e4m3<true>(r[k].z, r[k].w, pk);
                }
            }
        }

        #pragma unroll
        for (int off = 32; off; off >>= 1) {
            l1 += __shfl_down(l1, off, 64);
            l2 += __shfl_down(l2, off, 64);
        }
        if ((tid & 63) == 0) { red[tid >> 6] = l1; red2[tid >> 6] = l2; }
        __syncthreads();
        if (tid == 0) {
            float t1 = 0.f, t2 = 0.f;
            #pragma unroll
            for (int w = 0; w < 16; ++w) { t1 += red[w]; t2 += red2[w]; }
            if (is_t) tmsum[id] = t1;
            else { nsum[id - NT] = t1; ssum[id - NT] = t2; }
        }
        __syncthreads();   // buffers + red[] safe for next iteration
    }
}

// grid (7 qt, 8 b, KS). 4 waves; wave w owns t-tile w. C1=om.tm^T, C2=sig.tm^T.
__global__ __launch_bounds__(256) void dot_mfma_kernel(
    const _Float16* __restrict__ om, const _Float16* __restrict__ sg,
    const _Float16* __restrict__ tm,
    float* __restrict__ part_om, float* __restrict__ part_s)
{
    int qt = blockIdx.x, b = blockIdx.y, ks = blockIdx.z;
    int tid = threadIdx.x, lane = tid & 63, w = tid >> 6;
    int ra = lane & 15;
    int ko = (lane >> 4) * 8;
    const _Float16* pa = om + ((size_t)(b * QP + qt * 16 + ra)) * PP + ks * KCH + ko;
    const _Float16* ps = sg + ((size_t)(b * QP + qt * 16 + ra)) * PP + ks * KCH + ko;
    const _Float16* pb = tm + ((size_t)(b * TP + w * 16 + ra)) * PP + ks * KCH + ko;
    f32x4 accO = {0.f, 0.f, 0.f, 0.f};
    f32x4 accS = {0.f, 0.f, 0.f, 0.f};
    #pragma unroll 7
    for (int k = 0; k < KCH / 32; ++k) {
        f16x8 a = *(const f16x8*)(pa + (size_t)k * 32);
        f16x8 s = *(const f16x8*)(ps + (size_t)k * 32);
        f16x8 bb = *(const f16x8*)(pb + (size_t)k * 32);
        accO = __builtin_amdgcn_mfma_f32_16x16x32_f16(a, bb, accO, 0, 0, 0);
        accS = __builtin_amdgcn_mfma_f32_16x16x32_f16(s, bb, accS, 0, 0, 0);
    }
    int t = w * 16 + ra;
    int q = qt * 16 + (lane >> 4) * 4;
    size_t bse = (((size_t)ks * BB + b) * QP + q) * TP + t;
    #pragma unroll
    for (int r = 0; r < 4; ++r) {
        part_om[bse + (size_t)r * TP] = accO[r];
        part_s[bse + (size_t)r * TP] = accS[r];
    }
}

__global__ __launch_bounds__(256) void epilogue_kernel(
    const float* __restrict__ part_om, const float* __restrict__ part_s,
    const float* __restrict__ tmsum, const float* __restrict__ nsum,
    const float* __restrict__ ssum, const float* __restrict__ pred_logits,
    const float* __restrict__ pred_obj, const int* __restrict__ labels,
    float* __restrict__ out)
{
    int i = blockIdx.x * 256 + threadIdx.x;
    if (i >= BB * QQ * TT) return;
    int t = i % TT;
    int bq = i / TT;
    int b = bq / QQ, q = bq % QQ;
    float dO = 0.f, dS = 0.f;
    #pragma unroll
    for (int ks = 0; ks < KS; ++ks) {
        size_t o = (((size_t)ks * BB + b) * QP + q) * TP + t;
        dO += part_om[o];
        dS += part_s[o];
    }
    float ns = nsum[bq], ss = ssum[bq];
    float ts = tmsum[b * TT + t];
    float cmask = (ns - dO) * (1.f / PP);
    float cdice = 1.f - (2.f * dS + 1.f) / (ss + ts + 1.f);
    int label = labels[b * TT + t];
    float a0 = pred_obj[bq * 2], a1 = pred_obj[bq * 2 + 1];
    float prob;
    if (label == CC - 1) {
        prob = 1.f / (1.f + __expf(a0 - a1));
    } else {
        float pc = 1.f / (1.f + __expf(-pred_logits[(size_t)bq * CC + label]));
        float po = 1.f / (1.f + __expf(a1 - a0));
        prob = sqrtf(pc * po);
    }
    out[i] = 5.f * cmask - 2.f * prob + 5.f * cdice;
}

extern "C" void kernel_launch(void* const* d_in, const int* in_sizes, int n_in,
                              void* d_out, int out_size, void* d_ws, size_t ws_size,
                              hipStream_t stream) {
    const float* pred_logits = (const float*)d_in[0];
    const float* pred_obj    = (const float*)d_in[1];
    const float* pred_masks  = (const float*)d_in[2];
    const float* tgt_masks   = (const float*)d_in[3];
    const int*   tgt_labels  = (const int*)d_in[4];
    const float* coords      = (const float*)d_in[5];
    float* out = (float*)d_out;

    char* ws = (char*)d_ws;
    const size_t SZ_OM = (size_t)BB * QP * PP * 2;       // 22,478,848
    const size_t SZ_TM = (size_t)BB * TP * PP * 2;       // 12,845,056
    const size_t SZ_PT = (size_t)KS * BB * QP * TP * 4;  // 1,835,008
    _Float16* om  = (_Float16*)ws;
    _Float16* sg  = (_Float16*)(ws + SZ_OM);
    _Float16* tmm = (_Float16*)(ws + 2 * SZ_OM);
    float* part_om = (float*)(ws + 2 * SZ_OM + SZ_TM);
    float* part_s  = (float*)(ws + 2 * SZ_OM + SZ_TM + SZ_PT);
    float* tmsum   = (float*)(ws + 2 * SZ_OM + SZ_TM + 2 * SZ_PT);
    float* nsum    = tmsum + BB * TT;
    float* ssum    = nsum + BB * QQ;

    hipLaunchKernelGGL(sample_kernel, dim3(SGRID), dim3(1024), 0, stream,
                       tgt_masks, pred_masks, coords, tmm, om, sg, tmsum, nsum, ssum);
    hipLaunchKernelGGL(dot_mfma_kernel, dim3(QP / 16, BB, KS), dim3(256), 0, stream,
                       om, sg, tmm, part_om, part_s);
    hipLaunchKernelGGL(epilogue_kernel, dim3((BB * QQ * TT + 255) / 256), dim3(256),
                       0, stream,
                       part_om, part_s, tmsum, nsum, ssum,
                       pred_logits, pred_obj, tgt_labels, out);
}

// Round 8
// 124.430 us; speedup vs baseline: 1.0000x; 1.0000x over previous
//
#include <hip/hip_runtime.h>
#include <math.h>

#define BB 8
#define QQ 100
#define CC 41
#define TT 50
#define PP 12544        // = 49 * 256
#define QP 112          // padded Q rows (7 * 16)
#define TP 64           // padded T rows (4 * 16)
#define KS 8            // split-K over P
#define KCH (PP / KS)   // 1568
#define NT (BB * TT)    // 400
#define NMASK (NT + BB * QQ)   // 1200

typedef _Float16 f16x8 __attribute__((ext_vector_type(8)));
typedef float f32x4 __attribute__((ext_vector_type(4)));

#if defined(__has_builtin)
#if __has_builtin(__builtin_amdgcn_cvt_pk_fp8_f32) && __has_builtin(__builtin_amdgcn_cvt_f32_fp8)
#define HAVE_FP8CVT 1
#endif
#endif

__device__ __forceinline__ unsigned int cvt1_e4m3_sw(float x) {
    unsigned int u = __float_as_uint(x);
    unsigned int s = (u >> 24) & 0x80u;
    float ax = fminf(fabsf(x), 448.f);
    if (ax < 0.015625f) {
        unsigned int m = (unsigned int)rintf(ax * 512.f);
        return s | m;
    }
    unsigned int v = __float_as_uint(ax);
    v += 0x7FFFFu + ((v >> 20) & 1u);
    int e = (int)(v >> 23) - 127;
    unsigned int m = (v >> 20) & 7u;
    if (e < -6) { m = (unsigned int)rintf(ax * 512.f); return s | m; }
    unsigned int ee = (unsigned int)(e + 7);
    if (ee >= 16u) { ee = 15u; m = 6u; }
    return s | (ee << 3) | m;
}

template <bool HI>
__device__ __forceinline__ unsigned int pack2_e4m3(float a, float b, unsigned int old) {
#ifdef HAVE_FP8CVT
    return (unsigned int)__builtin_amdgcn_cvt_pk_fp8_f32(a, b, (int)old, HI);
#else
    unsigned int p = (cvt1_e4m3_sw(a) | (cvt1_e4m3_sw(b) << 8)) << (HI ? 16 : 0);
    unsigned int mask = HI ? 0x0000FFFFu : 0xFFFF0000u;
    return (old & mask) | p;
#endif
}

__device__ __forceinline__ float e4m3_to_f32(unsigned int byte) {
#ifdef HAVE_FP8CVT
    return __builtin_amdgcn_cvt_f32_fp8((int)byte, 0);
#else
    unsigned int s = byte >> 7, e = (byte >> 3) & 15u, m = byte & 7u;
    float v = e ? __uint_as_float(((e + 120u) << 23) | (m << 20))
                : (float)m * 0.001953125f;
    return s ? -v : v;
#endif
}

// Per-(b,p) bilinear table: 4 packed LDS byte addrs + 4 f16 weights (flags folded in).
__global__ __launch_bounds__(256) void table_kernel(
    const float* __restrict__ coords, uint4* __restrict__ table)
{
    int i = blockIdx.x * 256 + threadIdx.x;
    if (i >= BB * PP) return;
    float2 c = ((const float2*)coords)[i];
    float x = fmaf(c.x, 256.f, -0.5f);
    float y = fmaf(c.y, 256.f, -0.5f);
    float x0f = floorf(x), y0f = floorf(y);
    float wx = x - x0f, wy = y - y0f;
    int x0 = (int)x0f, y0 = (int)y0f;
    float fx0 = (x0 >= 0) ? 1.f : 0.f, fx1 = (x0 < 255) ? 1.f : 0.f;
    float fy0 = (y0 >= 0) ? 1.f : 0.f, fy1 = (y0 < 255) ? 1.f : 0.f;
    unsigned int x0c = (unsigned int)max(x0, 0), x1c = (unsigned int)min(x0 + 1, 255);
    unsigned int r0 = ((unsigned int)max(y0, 0)) << 8;
    unsigned int r1 = ((unsigned int)min(y0 + 1, 255)) << 8;
    float xa = (1.f - wx) * fx0, xb = wx * fx1;
    float ya = (1.f - wy) * fy0, yb = wy * fy1;
    union { unsigned int u; _Float16 h[2]; } w1, w2;
    w1.h[0] = (_Float16)(xa * ya); w1.h[1] = (_Float16)(xb * ya);
    w2.h[0] = (_Float16)(xa * yb); w2.h[1] = (_Float16)(xb * yb);
    uint4 t;
    t.x = (r0 + x0c) | ((r0 + x1c) << 16);
    t.y = (r1 + x0c) | ((r1 + x1c) << 16);
    t.z = w1.u; t.w = w2.u;
    table[i] = t;
}

__device__ __forceinline__ float tbl_interp(const unsigned char* __restrict__ mlds, uint4 t) {
    float v00 = e4m3_to_f32(mlds[t.x & 0xffffu]);
    float v01 = e4m3_to_f32(mlds[t.x >> 16]);
    float v10 = e4m3_to_f32(mlds[t.y & 0xffffu]);
    float v11 = e4m3_to_f32(mlds[t.y >> 16]);
    union { unsigned int u; _Float16 h[2]; } w1, w2;
    w1.u = t.z; w2.u = t.w;
    float acc = (float)w1.h[0] * v00;
    acc = fmaf((float)w1.h[1], v01, acc);
    acc = fmaf((float)w2.h[0], v10, acc);
    return fmaf((float)w2.h[1], v11, acc);
}

// One block per mask; full mask fp8 in LDS (64 KB); 2 blocks/CU (32 waves).
__global__ __launch_bounds__(1024, 8) void sample_kernel(
    const float* __restrict__ tgt_masks, const float* __restrict__ pred_masks,
    const uint4* __restrict__ table,
    _Float16* __restrict__ tm, _Float16* __restrict__ om, _Float16* __restrict__ sg,
    float* __restrict__ tmsum, float* __restrict__ nsum, float* __restrict__ ssum)
{
    __shared__ unsigned char mlds[65536];
    __shared__ float red[16], red2[16];
    int id = blockIdx.x;
    int tid = threadIdx.x;
    bool is_t = id < NT;
    int b;
    _Float16* dst;
    _Float16* dsg = nullptr;
    const float* m;
    if (is_t) {
        b = id / TT;
        m = tgt_masks + (size_t)id * 65536;
        dst = tm + ((size_t)b * TP + (id % TT)) * PP;
    } else {
        int bq = id - NT;
        b = bq / QQ;
        m = pred_masks + (size_t)bq * 65536;
        dst = om + ((size_t)b * QP + (bq % QQ)) * PP;
        dsg = sg + ((size_t)b * QP + (bq % QQ)) * PP;
    }
    const uint4* tb = table + (size_t)b * PP;

    // ---- load mask -> fp8 LDS (4 batches of 4 float4 per thread) ----
    {
        const float4* s4 = (const float4*)m;
        unsigned int* dl = (unsigned int*)mlds;
        #pragma unroll
        for (int bt = 0; bt < 4; ++bt) {
            float4 r0 = s4[bt * 4096 + tid];
            float4 r1 = s4[bt * 4096 + 1024 + tid];
            float4 r2 = s4[bt * 4096 + 2048 + tid];
            float4 r3 = s4[bt * 4096 + 3072 + tid];
            unsigned int pk;
            pk = pack2_e4m3<false>(r0.x, r0.y, 0u);
            dl[bt * 4096 + tid] = pack2_e4m3<true>(r0.z, r0.w, pk);
            pk = pack2_e4m3<false>(r1.x, r1.y, 0u);
            dl[bt * 4096 + 1024 + tid] = pack2_e4m3<true>(r1.z, r1.w, pk);
            pk = pack2_e4m3<false>(r2.x, r2.y, 0u);
            dl[bt * 4096 + 2048 + tid] = pack2_e4m3<true>(r2.z, r2.w, pk);
            pk = pack2_e4m3<false>(r3.x, r3.y, 0u);
            dl[bt * 4096 + 3072 + tid] = pack2_e4m3<true>(r3.z, r3.w, pk);
        }
    }
    __syncthreads();

    float l1 = 0.f, l2 = 0.f;

    if (is_t) {
        #pragma unroll
        for (int g = 0; g < 6; ++g) {
            int p = g * 2048 + 2 * tid;
            uint4 t0 = tb[p], t1 = tb[p + 1];
            float v1 = tbl_interp(mlds, t0);
            float v2 = tbl_interp(mlds, t1);
            union { unsigned int u; _Float16 h[2]; } o;
            o.h[0] = (_Float16)v1; o.h[1] = (_Float16)v2;
            *(unsigned int*)&dst[p] = o.u;
            l1 += v1 + v2;
        }
        if (tid < 128) {
            int p = 12288 + 2 * tid;
            uint4 t0 = tb[p], t1 = tb[p + 1];
            float v1 = tbl_interp(mlds, t0);
            float v2 = tbl_interp(mlds, t1);
            union { unsigned int u; _Float16 h[2]; } o;
            o.h[0] = (_Float16)v1; o.h[1] = (_Float16)v2;
            *(unsigned int*)&dst[p] = o.u;
            l1 += v1 + v2;
        }
    } else {
        #pragma unroll
        for (int g = 0; g < 6; ++g) {
            int p = g * 2048 + 2 * tid;
            uint4 t0 = tb[p], t1 = tb[p + 1];
            float v1 = tbl_interp(mlds, t0);
            float v2 = tbl_interp(mlds, t1);
            union { unsigned int u; _Float16 h[2]; } o;
            o.h[0] = (_Float16)v1; o.h[1] = (_Float16)v2;
            *(unsigned int*)&dst[p] = o.u;
            float e1 = __expf(-fabsf(v1)), e2 = __expf(-fabsf(v2));
            float q1 = 1.f / (1.f + e1), q2 = 1.f / (1.f + e2);
            float g1 = (v1 >= 0.f) ? q1 : e1 * q1;
            float g2 = (v2 >= 0.f) ? q2 : e2 * q2;
            union { unsigned int u; _Float16 h[2]; } os;
            os.h[0] = (_Float16)g1; os.h[1] = (_Float16)g2;
            *(unsigned int*)&dsg[p] = os.u;
            l1 += fmaxf(v1, 0.f) + __logf(1.f + e1)
                + fmaxf(v2, 0.f) + __logf(1.f + e2);
            l2 += g1 + g2;
        }
        if (tid < 128) {
            int p = 12288 + 2 * tid;
            uint4 t0 = tb[p], t1 = tb[p + 1];
            float v1 = tbl_interp(mlds, t0);
            float v2 = tbl_interp(mlds, t1);
            union { unsigned int u; _Float16 h[2]; } o;
            o.h[0] = (_Float16)v1; o.h[1] = (_Float16)v2;
            *(unsigned int*)&dst[p] = o.u;
            float e1 = __expf(-fabsf(v1)), e2 = __expf(-fabsf(v2));
            float q1 = 1.f / (1.f + e1), q2 = 1.f / (1.f + e2);
            float g1 = (v1 >= 0.f) ? q1 : e1 * q1;
            float g2 = (v2 >= 0.f) ? q2 : e2 * q2;
            union { unsigned int u; _Float16 h[2]; } os;
            os.h[0] = (_Float16)g1; os.h[1] = (_Float16)g2;
            *(unsigned int*)&dsg[p] = os.u;
            l1 += fmaxf(v1, 0.f) + __logf(1.f + e1)
                + fmaxf(v2, 0.f) + __logf(1.f + e2);
            l2 += g1 + g2;
        }
    }

    #pragma unroll
    for (int off = 32; off; off >>= 1) {
        l1 += __shfl_down(l1, off, 64);
        l2 += __shfl_down(l2, off, 64);
    }
    if ((tid & 63) == 0) { red[tid >> 6] = l1; red2[tid >> 6] = l2; }
    __syncthreads();
    if (tid == 0) {
        float t1 = 0.f, t2 = 0.f;
        #pragma unroll
        for (int w = 0; w < 16; ++w) { t1 += red[w]; t2 += red2[w]; }
        if (is_t) tmsum[id] = t1;
        else { nsum[id - NT] = t1; ssum[id - NT] = t2; }
    }
}

// grid (7 qt, 8 b, KS). 4 waves; wave w owns t-tile w. C1=om.tm^T, C2=sig.tm^T.
__global__ __launch_bounds__(256) void dot_mfma_kernel(
    const _Float16* __restrict__ om, const _Float16* __restrict__ sg,
    const _Float16* __restrict__ tm,
    float* __restrict__ part_om, float* __restrict__ part_s)
{
    int qt = blockIdx.x, b = blockIdx.y, ks = blockIdx.z;
    int tid = threadIdx.x, lane = tid & 63, w = tid >> 6;
    int ra = lane & 15;
    int ko = (lane >> 4) * 8;
    const _Float16* pa = om + ((size_t)(b * QP + qt * 16 + ra)) * PP + ks * KCH + ko;
    const _Float16* ps = sg + ((size_t)(b * QP + qt * 16 + ra)) * PP + ks * KCH + ko;
    const _Float16* pb = tm + ((size_t)(b * TP + w * 16 + ra)) * PP + ks * KCH + ko;
    f32x4 accO = {0.f, 0.f, 0.f, 0.f};
    f32x4 accS = {0.f, 0.f, 0.f, 0.f};
    #pragma unroll 7
    for (int k = 0; k < KCH / 32; ++k) {
        f16x8 a = *(const f16x8*)(pa + (size_t)k * 32);
        f16x8 s = *(const f16x8*)(ps + (size_t)k * 32);
        f16x8 bb = *(const f16x8*)(pb + (size_t)k * 32);
        accO = __builtin_amdgcn_mfma_f32_16x16x32_f16(a, bb, accO, 0, 0, 0);
        accS = __builtin_amdgcn_mfma_f32_16x16x32_f16(s, bb, accS, 0, 0, 0);
    }
    int t = w * 16 + ra;
    int q = qt * 16 + (lane >> 4) * 4;
    size_t bse = (((size_t)ks * BB + b) * QP + q) * TP + t;
    #pragma unroll
    for (int r = 0; r < 4; ++r) {
        part_om[bse + (size_t)r * TP] = accO[r];
        part_s[bse + (size_t)r * TP] = accS[r];
    }
}

__global__ __launch_bounds__(256) void epilogue_kernel(
    const float* __restrict__ part_om, const float* __restrict__ part_s,
    const float* __restrict__ tmsum, const float* __restrict__ nsum,
    const float* __restrict__ ssum, const float* __restrict__ pred_logits,
    const float* __restrict__ pred_obj, const int* __restrict__ labels,
    float* __restrict__ out)
{
    int i = blockIdx.x * 256 + threadIdx.x;
    if (i >= BB * QQ * TT) return;
    int t = i % TT;
    int bq = i / TT;
    int b = bq / QQ, q = bq % QQ;
    float dO = 0.f, dS = 0.f;
    #pragma unroll
    for (int ks = 0; ks < KS; ++ks) {
        size_t o = (((size_t)ks * BB + b) * QP + q) * TP + t;
        dO += part_om[o];
        dS += part_s[o];
    }
    float ns = nsum[bq], ss = ssum[bq];
    float ts = tmsum[b * TT + t];
    float cmask = (ns - dO) * (1.f / PP);
    float cdice = 1.f - (2.f * dS + 1.f) / (ss + ts + 1.f);
    int label = labels[b * TT + t];
    float a0 = pred_obj[bq * 2], a1 = pred_obj[bq * 2 + 1];
    float prob;
    if (label == CC - 1) {
        prob = 1.f / (1.f + __expf(a0 - a1));
    } else {
        float pc = 1.f / (1.f + __expf(-pred_logits[(size_t)bq * CC + label]));
        float po = 1.f / (1.f + __expf(a1 - a0));
        prob = sqrtf(pc * po);
    }
    out[i] = 5.f * cmask - 2.f * prob + 5.f * cdice;
}

extern "C" void kernel_launch(void* const* d_in, const int* in_sizes, int n_in,
                              void* d_out, int out_size, void* d_ws, size_t ws_size,
                              hipStream_t stream) {
    const float* pred_logits = (const float*)d_in[0];
    const float* pred_obj    = (const float*)d_in[1];
    const float* pred_masks  = (const float*)d_in[2];
    const float* tgt_masks   = (const float*)d_in[3];
    const int*   tgt_labels  = (const int*)d_in[4];
    const float* coords      = (const float*)d_in[5];
    float* out = (float*)d_out;

    char* ws = (char*)d_ws;
    const size_t SZ_TB = (size_t)BB * PP * 16;           // 1,605,632
    const size_t SZ_OM = (size_t)BB * QP * PP * 2;       // 22,478,848
    const size_t SZ_TM = (size_t)BB * TP * PP * 2;       // 12,845,056
    const size_t SZ_PT = (size_t)KS * BB * QP * TP * 4;  // 1,835,008
    uint4* table  = (uint4*)ws;
    _Float16* om  = (_Float16*)(ws + SZ_TB);
    _Float16* sg  = (_Float16*)(ws + SZ_TB + SZ_OM);
    _Float16* tmm = (_Float16*)(ws + SZ_TB + 2 * SZ_OM);
    float* part_om = (float*)(ws + SZ_TB + 2 * SZ_OM + SZ_TM);
    float* part_s  = (float*)(ws + SZ_TB + 2 * SZ_OM + SZ_TM + SZ_PT);
    float* tmsum   = (float*)(ws + SZ_TB + 2 * SZ_OM + SZ_TM + 2 * SZ_PT);
    float* nsum    = tmsum + BB * TT;
    float* ssum    = nsum + BB * QQ;

    hipLaunchKernelGGL(table_kernel, dim3((BB * PP + 255) / 256), dim3(256), 0, stream,
                       coords, table);
    hipLaunchKernelGGL(sample_kernel, dim3(NMASK), dim3(1024), 0, stream,
                       tgt_masks, pred_masks, table, tmm, om, sg, tmsum, nsum, ssum);
    hipLaunchKernelGGL(dot_mfma_kernel, dim3(QP / 16, BB, KS), dim3(256), 0, stream,
                       om, sg, tmm, part_om, part_s);
    hipLaunchKernelGGL(epilogue_kernel, dim3((BB * QQ * TT + 255) / 256), dim3(256),
                       0, stream,
                       part_om, part_s, tmsum, nsum, ssum,
                       pred_logits, pred_obj, tgt_labels, out);
}